// Round 10
// baseline (390.175 us; speedup 1.0000x reference)
//
#include <hip/hip_runtime.h>
#include <hip/hip_bf16.h>
#include <math.h>

typedef __hip_bfloat16 bf16;
typedef __attribute__((ext_vector_type(8))) short short8;
typedef __attribute__((ext_vector_type(4))) float floatx4;

constexpr int BB   = 2;
constexpr int SS   = 2048;
constexpr int DIMc = 1024;
constexpr int Hc   = 16;
constexpr int HDc  = 64;
constexpr int FFNc = 4096;
constexpr int TOK  = BB * SS;
constexpr float EPSc = 1e-5f;

typedef __attribute__((address_space(1))) void gvoid;
typedef __attribute__((address_space(3))) void lvoid;
__device__ __forceinline__ void lds16(const void* g, void* l) {
    __builtin_amdgcn_global_load_lds((gvoid*)g, (lvoid*)l, 16, 0, 0);
}
__device__ __forceinline__ float fexp2(float x) { return __builtin_amdgcn_exp2f(x); }

// tanh-form GELU via sigmoid, ~8 VALU + exp2 + rcp. Max abs dev ~3e-4.
__device__ __forceinline__ float fast_gelu(float x) {
    float x2 = x * x;
    float z = 0.7978845608028654f * x * __builtin_fmaf(0.044715f, x2, 1.0f);
    float e = fexp2(-2.885390081777927f * z);
    return x * __builtin_amdgcn_rcpf(1.0f + e);
}

// ---------------------------------------------------------------------------
// LayerNorm: block per token, fp32 in, bf16 out
// ---------------------------------------------------------------------------
__global__ __launch_bounds__(256) void ln_kernel(const float* __restrict__ x,
                                                 const float* __restrict__ g,
                                                 const float* __restrict__ b,
                                                 bf16* __restrict__ out) {
    int t = blockIdx.x;
    int tid = threadIdx.x;
    float4 v = ((const float4*)(x + (size_t)t * DIMc))[tid];
    float s  = v.x + v.y + v.z + v.w;
    float sq = v.x*v.x + v.y*v.y + v.z*v.z + v.w*v.w;
    for (int off = 1; off < 64; off <<= 1) {
        s  += __shfl_xor(s,  off, 64);
        sq += __shfl_xor(sq, off, 64);
    }
    __shared__ float ss[4], ssq[4];
    int wave = tid >> 6;
    if ((tid & 63) == 0) { ss[wave] = s; ssq[wave] = sq; }
    __syncthreads();
    s  = ss[0] + ss[1] + ss[2] + ss[3];
    sq = ssq[0] + ssq[1] + ssq[2] + ssq[3];
    float mu  = s * (1.0f / DIMc);
    float var = sq * (1.0f / DIMc) - mu * mu;
    float inv = rsqrtf(var + EPSc);
    float4 gg = ((const float4*)g)[tid];
    float4 bb = ((const float4*)b)[tid];
    size_t base = (size_t)t * DIMc + tid * 4;
    out[base + 0] = __float2bfloat16((v.x - mu) * inv * gg.x + bb.x);
    out[base + 1] = __float2bfloat16((v.y - mu) * inv * gg.y + bb.y);
    out[base + 2] = __float2bfloat16((v.z - mu) * inv * gg.z + bb.z);
    out[base + 3] = __float2bfloat16((v.w - mu) * inv * gg.w + bb.w);
}

// ---------------------------------------------------------------------------
// Fused split-K reduce + bias + residual + LayerNorm (block per token)
// ---------------------------------------------------------------------------
__global__ __launch_bounds__(256) void reduce_ln_kernel(const float* __restrict__ P,
                                                        const float* __restrict__ x,
                                                        const float* __restrict__ bias,
                                                        const float* __restrict__ g,
                                                        const float* __restrict__ b,
                                                        float* __restrict__ out,
                                                        bf16* __restrict__ hout) {
    int t = blockIdx.x;
    int tid = threadIdx.x;
    size_t off = (size_t)t * DIMc / 4 + tid;
    float4 v  = ((const float4*)x)[off];
    float4 p0 = ((const float4*)P)[off];
    float4 p1 = ((const float4*)P)[off + (size_t)TOK * DIMc / 4];
    float4 bv = ((const float4*)bias)[tid];
    v.x += p0.x + p1.x + bv.x;
    v.y += p0.y + p1.y + bv.y;
    v.z += p0.z + p1.z + bv.z;
    v.w += p0.w + p1.w + bv.w;
    ((float4*)out)[off] = v;

    float s  = v.x + v.y + v.z + v.w;
    float sq = v.x*v.x + v.y*v.y + v.z*v.z + v.w*v.w;
    for (int o = 1; o < 64; o <<= 1) {
        s  += __shfl_xor(s,  o, 64);
        sq += __shfl_xor(sq, o, 64);
    }
    __shared__ float ss[4], ssq[4];
    int wave = tid >> 6;
    if ((tid & 63) == 0) { ss[wave] = s; ssq[wave] = sq; }
    __syncthreads();
    s  = ss[0] + ss[1] + ss[2] + ss[3];
    sq = ssq[0] + ssq[1] + ssq[2] + ssq[3];
    float mu  = s * (1.0f / DIMc);
    float var = sq * (1.0f / DIMc) - mu * mu;
    float inv = rsqrtf(var + EPSc);
    float4 gg = ((const float4*)g)[tid];
    float4 bb = ((const float4*)b)[tid];
    size_t base = (size_t)t * DIMc + tid * 4;
    hout[base + 0] = __float2bfloat16((v.x - mu) * inv * gg.x + bb.x);
    hout[base + 1] = __float2bfloat16((v.y - mu) * inv * gg.y + bb.y);
    hout[base + 2] = __float2bfloat16((v.z - mu) * inv * gg.z + bb.z);
    hout[base + 3] = __float2bfloat16((v.w - mu) * inv * gg.w + bb.w);
}

// ---------------------------------------------------------------------------
// Elementwise split-K reduce + bias into out (fp32, holds residual)
// ---------------------------------------------------------------------------
__global__ __launch_bounds__(256) void reduce_add_kernel(const float* __restrict__ P,
                                                         const float* __restrict__ bias,
                                                         float* __restrict__ out) {
    size_t f = (size_t)blockIdx.x * 256 + threadIdx.x;   // float4 index
    float4 v  = ((float4*)out)[f];
    float4 p0 = ((const float4*)P)[f];
    float4 p1 = ((const float4*)P)[f + (size_t)TOK * DIMc / 4];
    float4 bv = ((const float4*)bias)[f & (DIMc / 4 - 1)];
    v.x += p0.x + p1.x + bv.x;
    v.y += p0.y + p1.y + bv.y;
    v.z += p0.z + p1.z + bv.z;
    v.w += p0.w + p1.w + bv.w;
    ((float4*)out)[f] = v;
}

// ---------------------------------------------------------------------------
// fp32 [K,N] -> bf16 [N,K] transpose-convert, 32x32 LDS tile
// ---------------------------------------------------------------------------
__global__ __launch_bounds__(256) void transpose_bf16(const float* __restrict__ in,
                                                      bf16* __restrict__ out,
                                                      int K, int N) {
    __shared__ float t[32][33];
    int k0 = blockIdx.y * 32, n0 = blockIdx.x * 32;
    int x = threadIdx.x & 31;
    int y = threadIdx.x >> 5;
#pragma unroll
    for (int i = 0; i < 4; ++i) {
        int k = y + i * 8;
        t[k][x] = in[(size_t)(k0 + k) * N + n0 + x];
    }
    __syncthreads();
#pragma unroll
    for (int i = 0; i < 4; ++i) {
        int n = y + i * 8;
        out[(size_t)(n0 + n) * K + k0 + x] = __float2bfloat16(t[x][n]);
    }
}

// ---------------------------------------------------------------------------
// V pre-transpose: qkv[b,s,2048+h*64+d] -> vT[((b*16+h)*64+d)*SS + s]  (bf16)
// ---------------------------------------------------------------------------
__global__ __launch_bounds__(256) void transpose_v(const bf16* __restrict__ qkv,
                                                   bf16* __restrict__ vT) {
    __shared__ short t[64][72];
    const int s0 = blockIdx.x * 64, h = blockIdx.y, b = blockIdx.z;
    const int tid = threadIdx.x;
    const short* qs = (const short*)qkv;
#pragma unroll
    for (int it = 0; it < 2; ++it) {
        int idx = it * 256 + tid;         // short8 id
        int r = idx >> 3, c = (idx & 7) * 8;
        *(short8*)&t[r][c] = *(const short8*)(qs + (size_t)(b * SS + s0 + r) * 3072
                                              + 2048 + h * 64 + c);
    }
    __syncthreads();
#pragma unroll
    for (int it = 0; it < 2; ++it) {
        int idx = it * 256 + tid;
        int d = idx >> 3, cs = (idx & 7) * 8;
        short8 v;
#pragma unroll
        for (int j = 0; j < 8; ++j) v[j] = t[cs + j][d];
        *(short8*)((short*)vT + ((size_t)(b * Hc + h) * 64 + d) * SS + s0 + cs) = v;
    }
}

// ---------------------------------------------------------------------------
// XCD-aware block remap for GEMMs (gridDim.y == 32).
// ---------------------------------------------------------------------------
__device__ __forceinline__ void xcd_remap(int& bx, int& by) {
    const int gn = gridDim.x;
    int lin = blockIdx.y * gn + blockIdx.x;
    int k8 = lin & 7, idx = lin >> 3;
    int hn = gn >> 1;
    by = (k8 >> 1) * 8 + (idx & 7);
    bx = (k8 & 1) * hn + (idx >> 3);
}

// ---------------------------------------------------------------------------
// bf16 MFMA GEMM, BK=64, bank-conflict-swizzled LDS.
// ACT=1: fast GELU. ROPE: apply rotary to q/k region (col < 2048).
// ---------------------------------------------------------------------------
template <int ACT, bool ROPE>
__global__ __launch_bounds__(256) void gemm_bt(const bf16* __restrict__ A,
                                               const bf16* __restrict__ Bt,
                                               const float* __restrict__ bias,
                                               bf16* __restrict__ Cout,
                                               int M, int N, int K) {
    constexpr int BK = 64;
    __shared__ bf16 As[2][128 * 32];
    __shared__ bf16 Bs[2][128 * 32];
    const int tid = threadIdx.x;
    const int wave = tid >> 6, lane = tid & 63;
    const int lane15 = lane & 15, lgrp = lane >> 4;
    const int wm = (wave >> 1) * 64, wn = (wave & 1) * 64;
    int bx, by; xcd_remap(bx, by);
    const int row0 = by * 128, col0 = bx * 128;

    floatx4 acc[4][4] = {};

    const int srow = wave * 16 + (lane >> 2);
    const int scol = (((lane & 3) + (srow >> 1)) & 3) * 8;
    const bf16* ga = A  + (size_t)(row0 + srow) * K + scol;
    const bf16* gb = Bt + (size_t)(col0 + srow) * K + scol;
    const int g_l = (lgrp - (lane15 >> 1)) & 3;

    for (int k0 = 0; k0 < K; k0 += BK) {
        __syncthreads();
#pragma unroll
        for (int p = 0; p < 4; ++p) {
            const size_t go = (size_t)((p & 1) * 64) * K + k0 + (p >> 1) * 32;
            lds16(ga + go, &As[p >> 1][(p & 1) * 2048 + wave * 512]);
            lds16(gb + go, &Bs[p >> 1][(p & 1) * 2048 + wave * 512]);
        }
        __syncthreads();
#pragma unroll
        for (int s = 0; s < 2; ++s) {
            short8 af[4], bfr[4];
#pragma unroll
            for (int i = 0; i < 4; ++i)
                af[i] = *(const short8*)(&As[s][(wm + i * 16 + lane15) * 32 + g_l * 8]);
#pragma unroll
            for (int j = 0; j < 4; ++j)
                bfr[j] = *(const short8*)(&Bs[s][(wn + j * 16 + lane15) * 32 + g_l * 8]);
#pragma unroll
            for (int i = 0; i < 4; ++i)
#pragma unroll
                for (int j = 0; j < 4; ++j)
                    acc[i][j] = __builtin_amdgcn_mfma_f32_16x16x32_bf16(af[i], bfr[j], acc[i][j], 0, 0, 0);
        }
    }

    const bool doRope = ROPE && (col0 < 2048);
    float invf0 = 0.f, invf1 = 0.f;
    if (ROPE) {
        invf0 = fexp2(-0.4152410118609203f * (float)lane15);
        invf1 = fexp2(-0.4152410118609203f * (float)(16 + lane15));
    }
    float bv[4];
#pragma unroll
    for (int j = 0; j < 4; ++j) bv[j] = bias[col0 + wn + j * 16 + lane15];

#pragma unroll
    for (int i = 0; i < 4; ++i) {
#pragma unroll
        for (int r = 0; r < 4; ++r) {
            int row = row0 + wm + i * 16 + lgrp * 4 + r;
            float v[4];
#pragma unroll
            for (int j = 0; j < 4; ++j) v[j] = acc[i][j][r] + bv[j];
            if (doRope) {
                float pos = (float)(row & (SS - 1));
                float s0, c0, s1, c1;
                __sincosf(pos * invf0, &s0, &c0);
                __sincosf(pos * invf1, &s1, &c1);
                float t0 = v[0] * c0 - v[2] * s0;
                float t1 = v[1] * c1 - v[3] * s1;
                float t2 = v[2] * c0 + v[0] * s0;
                float t3 = v[3] * c1 + v[1] * s1;
                v[0] = t0; v[1] = t1; v[2] = t2; v[3] = t3;
            }
#pragma unroll
            for (int j = 0; j < 4; ++j) {
                float o = v[j];
                if (ACT == 1) o = fast_gelu(o);
                Cout[(size_t)row * N + col0 + wn + j * 16 + lane15] = __float2bfloat16(o);
            }
        }
    }
}

// ---------------------------------------------------------------------------
// Split-K bf16 MFMA GEMM, BK=64, swizzled LDS, writes fp32 partials P[z][M][N]
// ---------------------------------------------------------------------------
__global__ __launch_bounds__(256) void gemm_bt_splitk(const bf16* __restrict__ A,
                                                      const bf16* __restrict__ Bt,
                                                      float* __restrict__ P,
                                                      int M, int N, int K, int KCH) {
    constexpr int BK = 64;
    __shared__ bf16 As[2][128 * 32];
    __shared__ bf16 Bs[2][128 * 32];
    const int tid = threadIdx.x;
    const int wave = tid >> 6, lane = tid & 63;
    const int lane15 = lane & 15, lgrp = lane >> 4;
    const int wm = (wave >> 1) * 64, wn = (wave & 1) * 64;
    int bx, by; xcd_remap(bx, by);
    const int row0 = by * 128, col0 = bx * 128;
    const int kbase = blockIdx.z * KCH;
    float* Cp = P + (size_t)blockIdx.z * M * N;

    floatx4 acc[4][4] = {};

    const int srow = wave * 16 + (lane >> 2);
    const int scol = (((lane & 3) + (srow >> 1)) & 3) * 8;
    const bf16* ga = A  + (size_t)(row0 + srow) * K + scol;
    const bf16* gb = Bt + (size_t)(col0 + srow) * K + scol;
    const int g_l = (lgrp - (lane15 >> 1)) & 3;

    for (int k0 = kbase; k0 < kbase + KCH; k0 += BK) {
        __syncthreads();
#pragma unroll
        for (int p = 0; p < 4; ++p) {
            const size_t go = (size_t)((p & 1) * 64) * K + k0 + (p >> 1) * 32;
            lds16(ga + go, &As[p >> 1][(p & 1) * 2048 + wave * 512]);
            lds16(gb + go, &Bs[p >> 1][(p & 1) * 2048 + wave * 512]);
        }
        __syncthreads();
#pragma unroll
        for (int s = 0; s < 2; ++s) {
            short8 af[4], bfr[4];
#pragma unroll
            for (int i = 0; i < 4; ++i)
                af[i] = *(const short8*)(&As[s][(wm + i * 16 + lane15) * 32 + g_l * 8]);
#pragma unroll
            for (int j = 0; j < 4; ++j)
                bfr[j] = *(const short8*)(&Bs[s][(wn + j * 16 + lane15) * 32 + g_l * 8]);
#pragma unroll
            for (int i = 0; i < 4; ++i)
#pragma unroll
                for (int j = 0; j < 4; ++j)
                    acc[i][j] = __builtin_amdgcn_mfma_f32_16x16x32_bf16(af[i], bfr[j], acc[i][j], 0, 0, 0);
        }
    }

#pragma unroll
    for (int i = 0; i < 4; ++i)
#pragma unroll
        for (int j = 0; j < 4; ++j) {
            int col = col0 + wn + j * 16 + lane15;
#pragma unroll
            for (int r = 0; r < 4; ++r) {
                int row = row0 + wm + i * 16 + lgrp * 4 + r;
                Cp[(size_t)row * N + col] = acc[i][j][r];
            }
        }
}

// ---------------------------------------------------------------------------
// MFMA flash attention, no-max softmax, split-KV=2, 128-key tiles,
// XCD-combo swizzle: flat dispatch id f -> (b,h,kc) = f&63 so all 16
// q-blocks of one (b,h,kc) land on one XCD (KV L2-resident there).
// Block = 4 waves x 32 q-rows = 128 q-rows; grid 1024 blocks.
// ---------------------------------------------------------------------------
__global__ __launch_bounds__(256) void attn_mfma(const bf16* __restrict__ qkv,
                                                 const bf16* __restrict__ vT,
                                                 const unsigned char* __restrict__ mask,
                                                 float* __restrict__ Op,
                                                 float* __restrict__ Lp) {
    __shared__ short Klds[4][64][32];     // [kh*2+s][key63][32]  16 KB (swizzled)
    __shared__ short Vlds[4][64][32];     // [kh*2+s][d][32]      16 KB (swizzled)
    __shared__ short Ps[4][32][72];       // per-wave P (Q-staging overlay) 18 KB
    __shared__ float mkf[128];

    // XCD-combo decode
    const int f = blockIdx.x + 16 * blockIdx.y + 256 * blockIdx.z;
    const int c = f & 63, qi = f >> 6;
    const int kc = c & 1, h = (c >> 1) & 15, b = c >> 5;
    const int q0 = qi * 128;

    const int tid = threadIdx.x;
    const int wave = tid >> 6, lane = tid & 63;
    const int lane15 = lane & 15, lgrp = lane >> 4;
    const short* qs = (const short*)qkv;
    const short* vs = (const short*)vT + (size_t)(b * Hc + h) * 64 * SS;
    const int g_l = (lgrp - (lane15 >> 1)) & 3;   // swizzled read slot

    // stage this wave's Q tile (32 rows x 64) fragment-major into Ps overlay
    short* qstage = &Ps[wave][0][0];
#pragma unroll
    for (int i = 0; i < 4; ++i) {
        int idx = i * 64 + lane;   // unit of 8 shorts
        int g = idx & 3, row = (idx >> 2) & 15, s = (idx >> 6) & 1, mi = idx >> 7;
        const short* gq = qs + (size_t)(b * SS + q0 + wave * 32 + mi * 16 + row) * 3072
                             + h * 64 + s * 32 + g * 8;
        lds16(gq, qstage + idx * 8);
    }
    __syncthreads();
    short8 aQ[2][2];
#pragma unroll
    for (int mi = 0; mi < 2; ++mi)
#pragma unroll
        for (int s = 0; s < 2; ++s)
            aQ[mi][s] = *(const short8*)(qstage + ((mi * 2 + s) * 16 + lane15) * 32 + lgrp * 8);

    const short8 bOnes = (short8)(short)0x3F80;   // bf16 1.0 x8
    floatx4 O[2][4] = {};
    floatx4 Lacc[2] = {};
    const float cscale = 0.18033688011112042f; // 0.125 * log2(e)

    for (int t = 0; t < 8; ++t) {
        const int k0 = kc * 1024 + t * 128;
        __syncthreads();   // WAR on Klds/Vlds + Ps overlay (first iter)
        // K tile 128 keys: [kh][sh][key63][g], per-row swizzle, 4 lds16/wave
#pragma unroll
        for (int i = 0; i < 4; ++i) {
            int idx = wave * 256 + i * 64 + lane;   // 0..1023
            int g = idx & 3, key63 = (idx >> 2) & 63, sh = (idx >> 8) & 1, kh = idx >> 9;
            int gsw = (g + (key63 >> 1)) & 3;
            const short* gk = qs + (size_t)(b * SS + k0 + kh * 64 + key63) * 3072 + 1024
                                 + h * 64 + sh * 32 + gsw * 8;
            lds16(gk, &Klds[0][0][0] + idx * 8);
        }
        // V tile: [kh][sh][d][g] with keys kh*64+sh*32+g*8.. from vT
#pragma unroll
        for (int i = 0; i < 4; ++i) {
            int idx = wave * 256 + i * 64 + lane;
            int g = idx & 3, d = (idx >> 2) & 63, sh = (idx >> 8) & 1, kh = idx >> 9;
            int gsw = (g + (d >> 1)) & 3;
            const short* gv = vs + (size_t)d * SS + k0 + kh * 64 + sh * 32 + gsw * 8;
            lds16(gv, &Vlds[0][0][0] + idx * 8);
        }
        if (tid < 32) {
            const unsigned char* mp = mask + b * SS + k0 + tid * 4;
#pragma unroll
            for (int j = 0; j < 4; ++j) mkf[tid * 4 + j] = mp[j] ? -1e30f : 0.0f;
        }
        __syncthreads();

#pragma unroll
        for (int kh = 0; kh < 2; ++kh) {
            // QK^T: 16 MFMA
            short8 bK[4][2];
#pragma unroll
            for (int j = 0; j < 4; ++j)
#pragma unroll
                for (int s = 0; s < 2; ++s)
                    bK[j][s] = *(const short8*)(&Klds[0][0][0]
                               + ((kh * 2 + s) * 64 + j * 16 + lane15) * 32 + g_l * 8);
            floatx4 Sf[2][4] = {};
#pragma unroll
            for (int mi = 0; mi < 2; ++mi)
#pragma unroll
                for (int j = 0; j < 4; ++j)
#pragma unroll
                    for (int s = 0; s < 2; ++s)
                        Sf[mi][j] = __builtin_amdgcn_mfma_f32_16x16x32_bf16(aQ[mi][s], bK[j][s], Sf[mi][j], 0, 0, 0);

            float mkv[4];
#pragma unroll
            for (int j = 0; j < 4; ++j) mkv[j] = mkf[kh * 64 + j * 16 + lane15];

            // P = exp2(scale*S + mask); C-layout: col=lane15+16j, row=lgrp*4+r
#pragma unroll
            for (int mi = 0; mi < 2; ++mi)
#pragma unroll
                for (int r = 0; r < 4; ++r)
#pragma unroll
                    for (int j = 0; j < 4; ++j) {
                        float p = fexp2(Sf[mi][j][r] * cscale + mkv[j]);
                        bf16 tt = __float2bfloat16(p);
                        Ps[wave][mi * 16 + lgrp * 4 + r][lane15 + 16 * j] = *(short*)&tt;
                    }

            // PV (16 MFMA) + L (4 MFMA); same-wave DS ops are in-order,
            // so no barrier needed around the per-wave Ps buffer
            short8 aP[2][2], bV[4][2];
#pragma unroll
            for (int mi = 0; mi < 2; ++mi)
#pragma unroll
                for (int s = 0; s < 2; ++s)
                    aP[mi][s] = *(const short8*)&Ps[wave][mi * 16 + lane15][s * 32 + lgrp * 8];
#pragma unroll
            for (int jd = 0; jd < 4; ++jd)
#pragma unroll
                for (int s = 0; s < 2; ++s)
                    bV[jd][s] = *(const short8*)(&Vlds[0][0][0]
                                + ((kh * 2 + s) * 64 + jd * 16 + lane15) * 32 + g_l * 8);
#pragma unroll
            for (int mi = 0; mi < 2; ++mi) {
#pragma unroll
                for (int jd = 0; jd < 4; ++jd)
#pragma unroll
                    for (int s = 0; s < 2; ++s)
                        O[mi][jd] = __builtin_amdgcn_mfma_f32_16x16x32_bf16(aP[mi][s], bV[jd][s], O[mi][jd], 0, 0, 0);
#pragma unroll
                for (int s = 0; s < 2; ++s)
                    Lacc[mi] = __builtin_amdgcn_mfma_f32_16x16x32_bf16(aP[mi][s], bOnes, Lacc[mi], 0, 0, 0);
            }
        }
    }

    // epilogue: unnormalized partials
    float* myOp = Op + (size_t)kc * TOK * DIMc;
#pragma unroll
    for (int mi = 0; mi < 2; ++mi)
#pragma unroll
        for (int r = 0; r < 4; ++r) {
            int q = q0 + wave * 32 + mi * 16 + lgrp * 4 + r;
            size_t rowoff = (size_t)(b * SS + q) * DIMc + h * 64 + lane15;
#pragma unroll
            for (int jd = 0; jd < 4; ++jd)
                myOp[rowoff + jd * 16] = O[mi][jd][r];
            if (lane15 == 0)
                Lp[((size_t)kc * TOK + b * SS + q) * Hc + h] = Lacc[mi][r];
        }
}

// ---------------------------------------------------------------------------
// Combine split-KV partials: ctx = (O0 + O1) / (L0 + L1), bf16 out
// ---------------------------------------------------------------------------
__global__ __launch_bounds__(256) void attn_combine(const float* __restrict__ Op,
                                                    const float* __restrict__ Lp,
                                                    bf16* __restrict__ ctx) {
    int t = blockIdx.x;
    int tid = threadIdx.x;
    int h = tid >> 4;
    size_t f = (size_t)t * (DIMc / 4) + tid;
    float4 p0 = ((const float4*)Op)[f];
    float4 p1 = ((const float4*)Op)[f + (size_t)TOK * DIMc / 4];
    float inv = 1.0f / (Lp[(size_t)t * Hc + h] + Lp[((size_t)TOK + t) * Hc + h]);
    size_t base = (size_t)t * DIMc + tid * 4;
    ctx[base + 0] = __float2bfloat16((p0.x + p1.x) * inv);
    ctx[base + 1] = __float2bfloat16((p0.y + p1.y) * inv);
    ctx[base + 2] = __float2bfloat16((p0.z + p1.z) * inv);
    ctx[base + 3] = __float2bfloat16((p0.w + p1.w) * inv);
}

// ---------------------------------------------------------------------------
extern "C" void kernel_launch(void* const* d_in, const int* in_sizes, int n_in,
                              void* d_out, int out_size, void* d_ws, size_t ws_size,
                              hipStream_t stream) {
    const float* x      = (const float*)d_in[0];
    const unsigned char* pmask = (const unsigned char*)d_in[1];
    const float* qkv_w  = (const float*)d_in[2];
    const float* qkv_b  = (const float*)d_in[3];
    const float* out_w  = (const float*)d_in[4];
    const float* out_b  = (const float*)d_in[5];
    const float* ln1_g  = (const float*)d_in[6];
    const float* ln1_b  = (const float*)d_in[7];
    const float* ln2_g  = (const float*)d_in[8];
    const float* ln2_b  = (const float*)d_in[9];
    const float* w1     = (const float*)d_in[10];
    const float* b1     = (const float*)d_in[11];
    const float* w2     = (const float*)d_in[12];
    const float* b2     = (const float*)d_in[13];
    float* out = (float*)d_out;

    char* ws = (char*)d_ws;
    bf16* wqkv_t = (bf16*)ws;                      ws += (size_t)3072 * 1024 * 2;
    bf16* wout_t = (bf16*)ws;                      ws += (size_t)1024 * 1024 * 2;
    bf16* w1_t   = (bf16*)ws;                      ws += (size_t)4096 * 1024 * 2;
    bf16* w2_t   = (bf16*)ws;                      ws += (size_t)1024 * 4096 * 2;
    bf16* h_bf   = (bf16*)ws;                      ws += (size_t)TOK * DIMc * 2;
    bf16* qkv_bf = (bf16*)ws;                      ws += (size_t)TOK * 3 * DIMc * 2;
    bf16* ctx_bf = (bf16*)ws;                      ws += (size_t)TOK * DIMc * 2;
    float* partial = (float*)ws;                   ws += (size_t)2 * TOK * DIMc * 4; // 32 MB
    float* Lp      = (float*)ws;                   ws += (size_t)2 * TOK * Hc * 4;   // 0.5 MB
    bf16* ffn1_bf = qkv_bf;          // overlay over dead qkv+ctx
    bf16* vT      = h_bf;            // overlay: h_bf dead between QKV gemm and reduce_ln

    transpose_bf16<<<dim3(3072 / 32, 1024 / 32), 256, 0, stream>>>(qkv_w, wqkv_t, 1024, 3072);
    transpose_bf16<<<dim3(1024 / 32, 1024 / 32), 256, 0, stream>>>(out_w, wout_t, 1024, 1024);
    transpose_bf16<<<dim3(4096 / 32, 1024 / 32), 256, 0, stream>>>(w1,    w1_t,   1024, 4096);
    transpose_bf16<<<dim3(1024 / 32, 4096 / 32), 256, 0, stream>>>(w2,    w2_t,   4096, 1024);

    ln_kernel<<<TOK, 256, 0, stream>>>(x, ln1_g, ln1_b, h_bf);
    // QKV + fused RoPE on q/k tiles
    gemm_bt<0, true><<<dim3(3072 / 128, TOK / 128), 256, 0, stream>>>(
        h_bf, wqkv_t, qkv_b, qkv_bf, TOK, 3 * DIMc, DIMc);
    // V pre-transpose (into dead h_bf region)
    transpose_v<<<dim3(SS / 64, Hc, BB), 256, 0, stream>>>(qkv_bf, vT);
    // attention: split-KV=2, XCD-combo swizzle, partials + combine
    attn_mfma<<<dim3(SS / 128, Hc, BB * 2), 256, 0, stream>>>(qkv_bf, vT, pmask, partial, Lp);
    attn_combine<<<TOK, 256, 0, stream>>>(partial, Lp, ctx_bf);

    // out projection: split-K=2 -> fp32 partials, then fused reduce+residual+LN2
    gemm_bt_splitk<<<dim3(1024 / 128, TOK / 128, 2), 256, 0, stream>>>(
        ctx_bf, wout_t, partial, TOK, DIMc, DIMc, 512);
    reduce_ln_kernel<<<TOK, 256, 0, stream>>>(partial, x, out_b, ln2_g, ln2_b, out, h_bf);

    // FFN1 + fast GELU
    gemm_bt<1, false><<<dim3(4096 / 128, TOK / 128), 256, 0, stream>>>(
        h_bf, w1_t, b1, ffn1_bf, TOK, FFNc, DIMc);
    // FFN2: split-K=2 -> partials, then elementwise reduce+bias into out
    gemm_bt_splitk<<<dim3(1024 / 128, TOK / 128, 2), 256, 0, stream>>>(
        ffn1_bf, w2_t, partial, TOK, DIMc, FFNc, 2048);
    reduce_add_kernel<<<TOK * DIMc / 4 / 256, 256, 0, stream>>>(partial, b2, out);
}